// Round 3
// baseline (208.309 us; speedup 1.0000x reference)
//
#include <hip/hip_runtime.h>
#include <math.h>

// Problem constants (from reference):
//   N=32, C=1, H=512, W=1024 -> HW = 524288 per batch row
//   SAMPLE_NUM = 5000 pairs per row -> 160000 pairs total
//   SIGMA = 0.03, ALPHA = 1.0, EPS = 1e-6, LOSS_WEIGHT = 1.0
#define SAMPLE_NUM 5000
#define HWSZ (512 * 1024)
#define SIGMA_F 0.03f
#define EPS_F 1e-6f

// Branchless per-pair body with all 6 gathers issued unconditionally and
// independently (only dependent on the idx loads) so they overlap in the
// memory system instead of forming a 3-deep serial latency chain.
template <bool MASK_I32>
__device__ __forceinline__ void
process_pairs(const float* __restrict__ pred, const float* __restrict__ targ,
              const void* __restrict__ mask_raw, const int* __restrict__ idxA,
              const int* __restrict__ idxB, int total, float& eq_sum,
              float& uneq_sum, float& valid) {
  const float hi = 1.0f + SIGMA_F;
  const float lo = 1.0f / (1.0f + SIGMA_F);
  const int* m32 = (const int*)mask_raw;
  const unsigned char* m8 = (const unsigned char*)mask_raw;

  const int i = blockIdx.x * blockDim.x + threadIdx.x;
  if (i >= total) return;

  const int n = i / SAMPLE_NUM;  // batch row (magic-mul)
  const long long base = (long long)n * HWSZ;
  const int a = idxA[i];
  const int b = idxB[i];
  const long long ia_off = base + a;
  const long long ib_off = base + b;

  // --- 6 independent gathers, no control flow between them ---
  const int ma = MASK_I32 ? m32[ia_off] : (int)m8[ia_off];
  const int mb = MASK_I32 ? m32[ib_off] : (int)m8[ib_off];
  const float tA = targ[ia_off];
  const float tB = targ[ib_off];
  const float iA = pred[ia_off];
  const float iB = pred[ib_off];

  // --- branchless math ---
  const bool cm = (ma != 0) && (mb != 0);
  const float ratio = tA / (tB + EPS_F);
  const bool is_eq = (ratio < hi) && (ratio > lo);
  const float d = iA - iB;
  const float label = (ratio >= hi) ? 1.0f : -1.0f;
  const float x = (iB - iA) * label;
  const float u = (x > 20.0f) ? x : log1pf(expf(x));  // log1p(exp(x))

  eq_sum += (cm && is_eq) ? d * d : 0.0f;   // ALPHA == 1.0
  uneq_sum += (cm && !is_eq) ? u : 0.0f;
  valid += cm ? 1.0f : 0.0f;
}

// ws layout (16 bytes, zeroed via hipMemsetAsync each launch):
//   ws[0] = equal_loss sum, ws[1] = unequal_loss sum,
//   ws[2] = valid count,    ws[3] = done-block ticket (uint32)
__global__ void __launch_bounds__(256)
ranking_loss_kernel(const float* __restrict__ pred,
                    const float* __restrict__ targ,
                    const void* __restrict__ mask_raw,
                    const int* __restrict__ idxA,
                    const int* __restrict__ idxB,
                    float* __restrict__ out,
                    float* __restrict__ ws,
                    int total) {
  // --- Mask layout detection (thread-uniform, L2-broadcast reads) ---
  // int32 bools: every word is 0/1.  Byte bools: a uint32 view exceeds 1
  // with P=7/8 per word. 32 words -> misdetect P = 8^-32.
  const unsigned int* mw = (const unsigned int*)mask_raw;
  bool mask_is_i32 = true;
  #pragma unroll
  for (int w = 0; w < 32; ++w) {
    if (mw[w] > 1u) mask_is_i32 = false;
  }

  float eq_sum = 0.0f, uneq_sum = 0.0f, valid = 0.0f;
  if (mask_is_i32) {
    process_pairs<true>(pred, targ, mask_raw, idxA, idxB, total, eq_sum,
                        uneq_sum, valid);
  } else {
    process_pairs<false>(pred, targ, mask_raw, idxA, idxB, total, eq_sum,
                         uneq_sum, valid);
  }

  // Wave-64 shuffle reduction
  #pragma unroll
  for (int off = 32; off > 0; off >>= 1) {
    eq_sum   += __shfl_down(eq_sum, off, 64);
    uneq_sum += __shfl_down(uneq_sum, off, 64);
    valid    += __shfl_down(valid, off, 64);
  }

  __shared__ float s_eq[4], s_un[4], s_va[4];
  const int lane = threadIdx.x & 63;
  const int wave = threadIdx.x >> 6;
  if (lane == 0) {
    s_eq[wave] = eq_sum;
    s_un[wave] = uneq_sum;
    s_va[wave] = valid;
  }
  __syncthreads();

  if (threadIdx.x == 0) {
    float e = 0.0f, u = 0.0f, v = 0.0f;
    const int nwaves = blockDim.x >> 6;
    for (int w = 0; w < nwaves; ++w) {
      e += s_eq[w];
      u += s_un[w];
      v += s_va[w];
    }
    atomicAdd(&ws[0], e);
    atomicAdd(&ws[1], u);
    atomicAdd(&ws[2], v);
    __threadfence();
    const unsigned int ticket = atomicAdd((unsigned int*)&ws[3], 1u);
    if (ticket == gridDim.x - 1) {
      // Device-scope coherent readback across non-coherent per-XCD L2s.
      const float eqs = atomicAdd(&ws[0], 0.0f);
      const float uns = atomicAdd(&ws[1], 0.0f);
      const float vas = atomicAdd(&ws[2], 0.0f);
      out[0] = (eqs + uns) / (vas + EPS_F);  // ALPHA=1, LOSS_WEIGHT=1
    }
  }
}

extern "C" void kernel_launch(void* const* d_in, const int* in_sizes, int n_in,
                              void* d_out, int out_size, void* d_ws,
                              size_t ws_size, hipStream_t stream) {
  const float* pred = (const float*)d_in[0];
  const float* targ = (const float*)d_in[1];
  const void* mask = d_in[2];  // bool array; layout detected on device
  const int* idxA = (const int*)d_in[3];
  const int* idxB = (const int*)d_in[4];
  float* out = (float*)d_out;
  float* ws = (float*)d_ws;

  const int total = in_sizes[3];  // N * SAMPLE_NUM = 160000

  hipMemsetAsync(d_ws, 0, 4 * sizeof(float), stream);

  const int block = 256;
  const int grid = (total + block - 1) / block;  // 625 blocks, 1 pair/thread
  ranking_loss_kernel<<<grid, block, 0, stream>>>(pred, targ, mask, idxA, idxB,
                                                  out, ws, total);
}

// Round 4
// 170.649 us; speedup vs baseline: 1.2207x; 1.2207x over previous
//
#include <hip/hip_runtime.h>
#include <math.h>

// Problem constants (from reference):
//   N=32, C=1, H=512, W=1024 -> HW = 524288 per batch row
//   SAMPLE_NUM = 5000 pairs per row -> 160000 pairs total
//   SIGMA = 0.03, ALPHA = 1.0, EPS = 1e-6, LOSS_WEIGHT = 1.0
#define SAMPLE_NUM 5000
#define HWSZ (512 * 1024)
#define SIGMA_F 0.03f
#define EPS_F 1e-6f
#define BLOCK 256

// R4 design notes:
//  - R3 counters showed dur identical for cache-warm replays (hbm_bytes 80 kB)
//    vs cold (59 MB) -> NOT memory-bound. Fixed ~45 us attributed to 2500
//    serialized same-line device-scope atomics (625 blocks x 4 RMWs).
//  - Fix: per-block partial -> private ws slot via plain stores; separate
//    1-block finalize kernel reduces slots. Kernel boundary = release/acquire,
//    so no atomics, no fences, no memset needed (every slot written).
//  - Gathers: conditional again (exec-masked lanes don't issue transactions;
//    ~3 gathers/pair avg vs 6 unconditional), with targ+pred in ONE latency
//    round: chain is idx -> mask -> {tA,tB,iA,iB}.

template <bool MASK_I32>
__device__ __forceinline__ void
pair_body(const float* __restrict__ pred, const float* __restrict__ targ,
          const void* __restrict__ mask_raw, const int* __restrict__ idxA,
          const int* __restrict__ idxB, int total, float& eq_sum,
          float& uneq_sum, float& valid) {
  const float hi = 1.0f + SIGMA_F;
  const float lo = 1.0f / (1.0f + SIGMA_F);
  const int* m32 = (const int*)mask_raw;
  const unsigned char* m8 = (const unsigned char*)mask_raw;

  const int i = blockIdx.x * BLOCK + threadIdx.x;
  if (i >= total) return;

  const int n = i / SAMPLE_NUM;  // magic-mul division
  const long long base = (long long)n * HWSZ;
  const int a = idxA[i];
  const int b = idxB[i];
  const long long ia_off = base + a;
  const long long ib_off = base + b;

  // Round 2: two independent mask gathers.
  const int ma = MASK_I32 ? m32[ia_off] : (int)m8[ia_off];
  const int mb = MASK_I32 ? m32[ib_off] : (int)m8[ib_off];

  if (ma && mb) {
    // Round 3: four independent gathers, only for valid lanes (~25%).
    const float tA = targ[ia_off];
    const float tB = targ[ib_off];
    const float iA = pred[ia_off];
    const float iB = pred[ib_off];

    valid += 1.0f;
    const float ratio = tA / (tB + EPS_F);
    if (ratio < hi && ratio > lo) {
      const float d = iA - iB;
      eq_sum += d * d;  // ALPHA == 1.0
    } else {
      const float label = (ratio >= hi) ? 1.0f : -1.0f;
      const float x = (iB - iA) * label;
      uneq_sum += (x > 20.0f) ? x : log1pf(expf(x));  // log1p(exp(x))
    }
  }
}

// Kernel 1: per-block partials -> ws[3*blockIdx + {0,1,2}] (plain stores).
__global__ void __launch_bounds__(BLOCK)
ranking_loss_partial(const float* __restrict__ pred,
                     const float* __restrict__ targ,
                     const void* __restrict__ mask_raw,
                     const int* __restrict__ idxA,
                     const int* __restrict__ idxB,
                     float* __restrict__ ws, int total) {
  // Mask layout detection (thread-uniform). int32 bools: every word is 0/1.
  // Byte bools: uint32 view >1 with P=7/8 per word; 32 words -> P_err=8^-32.
  const unsigned int* mw = (const unsigned int*)mask_raw;
  bool mask_is_i32 = true;
  #pragma unroll
  for (int w = 0; w < 32; ++w) {
    if (mw[w] > 1u) mask_is_i32 = false;
  }

  float eq_sum = 0.0f, uneq_sum = 0.0f, valid = 0.0f;
  if (mask_is_i32) {
    pair_body<true>(pred, targ, mask_raw, idxA, idxB, total, eq_sum, uneq_sum,
                    valid);
  } else {
    pair_body<false>(pred, targ, mask_raw, idxA, idxB, total, eq_sum, uneq_sum,
                     valid);
  }

  // Wave-64 shuffle reduction
  #pragma unroll
  for (int off = 32; off > 0; off >>= 1) {
    eq_sum   += __shfl_down(eq_sum, off, 64);
    uneq_sum += __shfl_down(uneq_sum, off, 64);
    valid    += __shfl_down(valid, off, 64);
  }

  __shared__ float s_eq[4], s_un[4], s_va[4];
  const int lane = threadIdx.x & 63;
  const int wave = threadIdx.x >> 6;
  if (lane == 0) {
    s_eq[wave] = eq_sum;
    s_un[wave] = uneq_sum;
    s_va[wave] = valid;
  }
  __syncthreads();

  if (threadIdx.x == 0) {
    float e = 0.0f, u = 0.0f, v = 0.0f;
    #pragma unroll
    for (int w = 0; w < BLOCK / 64; ++w) {
      e += s_eq[w];
      u += s_un[w];
      v += s_va[w];
    }
    float* slot = ws + 3 * blockIdx.x;
    slot[0] = e;
    slot[1] = u;
    slot[2] = v;
  }
}

// Kernel 2: single block reduces all per-block slots and writes the scalar.
__global__ void __launch_bounds__(BLOCK)
ranking_loss_finalize(const float* __restrict__ ws, float* __restrict__ out,
                      int nblocks) {
  float e = 0.0f, u = 0.0f, v = 0.0f;
  for (int s = threadIdx.x; s < nblocks; s += BLOCK) {
    e += ws[3 * s + 0];
    u += ws[3 * s + 1];
    v += ws[3 * s + 2];
  }
  #pragma unroll
  for (int off = 32; off > 0; off >>= 1) {
    e += __shfl_down(e, off, 64);
    u += __shfl_down(u, off, 64);
    v += __shfl_down(v, off, 64);
  }
  __shared__ float s_e[4], s_u[4], s_v[4];
  const int lane = threadIdx.x & 63;
  const int wave = threadIdx.x >> 6;
  if (lane == 0) {
    s_e[wave] = e;
    s_u[wave] = u;
    s_v[wave] = v;
  }
  __syncthreads();
  if (threadIdx.x == 0) {
    float te = 0.0f, tu = 0.0f, tv = 0.0f;
    #pragma unroll
    for (int w = 0; w < BLOCK / 64; ++w) {
      te += s_e[w];
      tu += s_u[w];
      tv += s_v[w];
    }
    out[0] = (te + tu) / (tv + EPS_F);  // ALPHA=1, LOSS_WEIGHT=1
  }
}

extern "C" void kernel_launch(void* const* d_in, const int* in_sizes, int n_in,
                              void* d_out, int out_size, void* d_ws,
                              size_t ws_size, hipStream_t stream) {
  const float* pred = (const float*)d_in[0];
  const float* targ = (const float*)d_in[1];
  const void* mask = d_in[2];  // bool array; layout detected on device
  const int* idxA = (const int*)d_in[3];
  const int* idxB = (const int*)d_in[4];
  float* out = (float*)d_out;
  float* ws = (float*)d_ws;

  const int total = in_sizes[3];  // N * SAMPLE_NUM = 160000
  const int grid = (total + BLOCK - 1) / BLOCK;  // 625 blocks

  // Every ws slot is written unconditionally by kernel 1 -> no memset needed.
  ranking_loss_partial<<<grid, BLOCK, 0, stream>>>(pred, targ, mask, idxA,
                                                   idxB, ws, total);
  ranking_loss_finalize<<<1, BLOCK, 0, stream>>>(ws, out, grid);
}